// Round 7
// baseline (365.234 us; speedup 1.0000x reference)
//
#include <hip/hip_runtime.h>

#define H 32
#define SEQ 512
#define NR 8            // batch rows per block
#define NTHREADS 256    // 4 waves; grid = 4096/8 = 512 -> 2 independent blocks/CU
#define HSTRIDE 40      // halves per h-row (16 rows allocated; 8 used)

typedef _Float16 half8 __attribute__((ext_vector_type(8)));
typedef __attribute__((ext_vector_type(4))) float f32x4;

#define L2E 1.44269504088896340736f

__device__ __forceinline__ float rcp_(float x)  { return __builtin_amdgcn_rcpf(x); }
__device__ __forceinline__ float exp2_(float x) { return __builtin_amdgcn_exp2f(x); }  // raw v_exp_f32
__device__ __forceinline__ float bperm_f(int idx, float v) {
    return __int_as_float(__builtin_amdgcn_ds_bpermute(idx, __float_as_int(v)));
}
#define MFMA16(A, B, C) __builtin_amdgcn_mfma_f32_16x16x32_f16((A), (B), (C), 0, 0, 0)

__global__ __launch_bounds__(NTHREADS, 2) void lstm_kernel(
    const float* __restrict__ x,      // [4096,512]
    const float* __restrict__ w_ih0,  // [128,1]
    const float* __restrict__ w_hh0,  // [128,32]
    const float* __restrict__ b_ih0, const float* __restrict__ b_hh0,
    const float* __restrict__ w_ih1,  // [128,32]
    const float* __restrict__ w_hh1,  // [128,32]
    const float* __restrict__ b_ih1, const float* __restrict__ b_hh1,
    const float* __restrict__ fc1_w,  // [16,32]
    const float* __restrict__ fc1_b,  // [16]
    const float* __restrict__ fc2_w,  // [1,16]
    const float* __restrict__ fc2_b,  // [1]
    float* __restrict__ out)          // [4096]
{
    __shared__ __align__(16) float    xbufT[SEQ * NR];         // 16 KB, [step][row]
    __shared__ __align__(16) _Float16 h1s[2][16 * HSTRIDE];    // ping-pong h1 (fp16), 16 rows alloc
    __shared__ __align__(16) _Float16 h2s[2][16 * HSTRIDE];    // ping-pong h2 (fp16)
    __shared__ __align__(16) float    h2f[NR * 33];
    __shared__ __align__(16) float    yb[NR * 17];

    const int tid  = threadIdx.x;
    const int lane = tid & 63;
    const int wv   = tid >> 6;          // wave id 0..3; owns tiles {wv, wv+4}
    const int c    = lane & 15;         // frag free-index / batch col (0..7 valid)
    const int q    = lane >> 4;         // k-quad / D row-group
    const int r0   = blockIdx.x * NR;

    // ---- stage x transposed: xbufT[s][row]; 256 threads, 16 steps each ----
    {
        const int row = tid >> 5;           // 0..7
        const int s0  = (tid & 31) * 16;    // 16 steps per thread
        const float* xr = x + (size_t)(r0 + row) * SEQ + s0;
        #pragma unroll
        for (int i = 0; i < 16; i += 4) {
            float4 v = *(const float4*)&xr[i];
            xbufT[(s0 + i + 0) * NR + row] = v.x;
            xbufT[(s0 + i + 1) * NR + row] = v.y;
            xbufT[(s0 + i + 2) * NR + row] = v.z;
            xbufT[(s0 + i + 3) * NR + row] = v.w;
        }
    }
    for (int i = tid; i < 16 * HSTRIDE; i += NTHREADS) {
        h1s[0][i] = (_Float16)0.f; h1s[1][i] = (_Float16)0.f;
        h2s[0][i] = (_Float16)0.f; h2s[1][i] = (_Float16)0.f;
    }

    // ---- W fragments (A-operand), permuted: tile ti frag-row r -> (gate r&3, unit 4ti + r>>2)
    // gate scales folded (i,f,o: -L2E ; g: +2L2E) so EW uses raw v_exp_f32.
    const float gsc[4] = { -L2E, -L2E, 2.f * L2E, -L2E };
    const int kb  = 8 * q;
    const float wsc = gsc[c & 3];

    half8 w0hA, w0lA, w0hB, w0lB;          // w_hh0 tiles A,B (hi/lo)
    half8 wihA, wilA, wihB, wilB;          // w_ih1 tiles A,B
    half8 whhA, whlA, whhB, whlB;          // w_hh1 tiles A,B
    {
        const int wrA = (c & 3) * H + 4 * wv + (c >> 2);            // tile A = wv
        const int wrB = (c & 3) * H + 4 * (wv + 4) + (c >> 2);      // tile B = wv+4
        const float *pA, *pB;
        pA = &w_hh0[wrA * H + kb]; pB = &w_hh0[wrB * H + kb];
        #pragma unroll
        for (int j = 0; j < 8; ++j) {
            float vA = pA[j] * wsc; _Float16 hA = (_Float16)vA; w0hA[j] = hA; w0lA[j] = (_Float16)(vA - (float)hA);
            float vB = pB[j] * wsc; _Float16 hB = (_Float16)vB; w0hB[j] = hB; w0lB[j] = (_Float16)(vB - (float)hB);
        }
        pA = &w_ih1[wrA * H + kb]; pB = &w_ih1[wrB * H + kb];
        #pragma unroll
        for (int j = 0; j < 8; ++j) {
            float vA = pA[j] * wsc; _Float16 hA = (_Float16)vA; wihA[j] = hA; wilA[j] = (_Float16)(vA - (float)hA);
            float vB = pB[j] * wsc; _Float16 hB = (_Float16)vB; wihB[j] = hB; wilB[j] = (_Float16)(vB - (float)hB);
        }
        pA = &w_hh1[wrA * H + kb]; pB = &w_hh1[wrB * H + kb];
        #pragma unroll
        for (int j = 0; j < 8; ++j) {
            float vA = pA[j] * wsc; _Float16 hA = (_Float16)vA; whhA[j] = hA; whlA[j] = (_Float16)(vA - (float)hA);
            float vB = pB[j] * wsc; _Float16 hB = (_Float16)vB; whhB[j] = hB; whlB[j] = (_Float16)(vB - (float)hB);
        }
    }

    // ---- pre-rebalance C-init biases: lane (q,·) of tile ti holds unit 4ti+q, acc-reg j = gate j
    f32x4 b1A, b1B, b2A, b2B;
    {
        const int uA = 4 * wv + q, uB = 4 * (wv + 4) + q;
        #pragma unroll
        for (int j = 0; j < 4; ++j) {
            b1A[j] = (b_ih0[j * H + uA] + b_hh0[j * H + uA]) * gsc[j];
            b1B[j] = (b_ih0[j * H + uB] + b_hh0[j * H + uB]) * gsc[j];
            b2A[j] = (b_ih1[j * H + uA] + b_hh1[j * H + uA]) * gsc[j];
            b2B[j] = (b_ih1[j * H + uB] + b_hh1[j * H + uB]) * gsc[j];
        }
    }

    // ---- post-rebalance cell coords: lane l -> (row l&7, tile (l>>3)&1, quad l>>4)
    const int prow  = lane & 7;
    const int upost = 4 * (wv + 4 * ((lane >> 3) & 1)) + (lane >> 4);
    float wx[4];
    #pragma unroll
    for (int j = 0; j < 4; ++j) wx[j] = w_ih0[j * H + upost] * gsc[j];

    float c1 = 0.f, c2 = 0.f, h2last = 0.f;

    const int fofs  = c * HSTRIDE + kb;          // b128 frag read offset (halves)
    const int whofs = prow * HSTRIDE + upost;    // h write offset (halves)
    const int bpi   = (lane & ~8) * 4;           // bpermute byte index

    __syncthreads();

    // shared-rcp LSTM cell: 5 v_exp + 2 v_rcp
    auto cell = [&](const f32x4& g, float& cst) -> float {
        float ei = exp2_(g[0]);
        float ef = exp2_(g[1]);
        float eg = exp2_(g[2]);
        float eo = exp2_(g[3]);
        float A  = 1.f + ei;
        float F  = 1.f + ef;
        float Gp = eg + 1.f, Gm = eg - 1.f;
        float t1 = A * Gp;
        float num = fmaf(cst, t1, Gm * F);
        float cn  = num * rcp_(F * t1);
        cn = __builtin_amdgcn_fmed3f(cn, -12.f, 12.f);
        cst = cn;
        float ec = exp2_(cn * (2.f * L2E));
        return (ec - 1.f) * rcp_((1.f + eo) * (ec + 1.f));
    };

    // rebalance: lanes bit3=1 take tile-B acc from lane l-8; bit3=0 keep tile-A
    const bool takeB = (lane & 8) != 0;
    auto rebal = [&](const f32x4& A, const f32x4& B) -> f32x4 {
        f32x4 r;
        #pragma unroll
        for (int j = 0; j < 4; ++j) {
            float pb = bperm_f(bpi, B[j]);
            r[j] = takeB ? pb : A[j];
        }
        return r;
    };

    // iter t: L1 step t, L2 step t-1. One barrier per iter.
    auto do_step = [&](const _Float16* __restrict__ h1r, const _Float16* __restrict__ h2r,
                       _Float16* __restrict__ h1w, _Float16* __restrict__ h2w,
                       int t, bool e1, bool e2) {
        half8 a1 = *(const half8*)(h1r + fofs);
        half8 a2 = *(const half8*)(h2r + fofs);
        f32x4 g1A = b1A, g1B = b1B, gaA = b2A, gaB = b2B;
        f32x4 gbA = {0.f, 0.f, 0.f, 0.f}, gbB = {0.f, 0.f, 0.f, 0.f};
        g1A = MFMA16(w0hA, a1, g1A);  g1B = MFMA16(w0hB, a1, g1B);
        gaA = MFMA16(wihA, a1, gaA);  gaB = MFMA16(wihB, a1, gaB);
        gbA = MFMA16(whhA, a2, gbA);  gbB = MFMA16(whhB, a2, gbB);
        g1A = MFMA16(w0lA, a1, g1A);  g1B = MFMA16(w0lB, a1, g1B);
        gaA = MFMA16(wilA, a1, gaA);  gaB = MFMA16(wilB, a1, gaB);
        gbA = MFMA16(whlA, a2, gbA);  gbB = MFMA16(whlB, a2, gbB);
        f32x4 g2A, g2B;
        #pragma unroll
        for (int j = 0; j < 4; ++j) { g2A[j] = gaA[j] + gbA[j]; g2B[j] = gaB[j] + gbB[j]; }
        f32x4 g1 = rebal(g1A, g1B);
        f32x4 g2 = rebal(g2A, g2B);
        if (e1) {
            float xv = xbufT[t * NR + prow];
            #pragma unroll
            for (int j = 0; j < 4; ++j) g1[j] = fmaf(xv, wx[j], g1[j]);
            float h1v = cell(g1, c1);
            h1w[whofs] = (_Float16)h1v;
        }
        if (e2) {
            float h2v = cell(g2, c2);
            h2last = h2v;
            h2w[whofs] = (_Float16)h2v;
        }
        __syncthreads();
    };

    do_step(h1s[0], h2s[0], h1s[1], h2s[1], 0, true, false);
    for (int tt = 0; tt < 255; ++tt) {
        int t = 1 + 2 * tt;
        do_step(h1s[1], h2s[1], h1s[0], h2s[0], t,     true, true);
        do_step(h1s[0], h2s[0], h1s[1], h2s[1], t + 1, true, true);
    }
    do_step(h1s[1], h2s[1], h1s[0], h2s[0], 511, true, true);
    do_step(h1s[0], h2s[0], h1s[1], h2s[1], 512, false, true);

    // ---- FC head: all 256 threads hold one h2 cell (row prow, unit upost) ----
    h2f[prow * 33 + upost] = h2last;
    __syncthreads();
    if (tid < NR * 16) {
        int rr = tid >> 4, j = tid & 15;
        float acc = fc1_b[j];
        #pragma unroll
        for (int k = 0; k < H; ++k) acc += fc1_w[j * H + k] * h2f[rr * 33 + k];
        acc = acc >= 0.f ? acc : 0.2f * acc;
        yb[rr * 17 + j] = acc * fc2_w[j];
    }
    __syncthreads();
    if (tid < NR) {
        float acc = fc2_b[0];
        #pragma unroll
        for (int j = 0; j < 16; ++j) acc += yb[tid * 17 + j];
        out[r0 + tid] = acc;
    }
}

extern "C" void kernel_launch(void* const* d_in, const int* in_sizes, int n_in,
                              void* d_out, int out_size, void* d_ws, size_t ws_size,
                              hipStream_t stream) {
    const float* x     = (const float*)d_in[0];
    const float* w_ih0 = (const float*)d_in[1];
    const float* w_hh0 = (const float*)d_in[2];
    const float* b_ih0 = (const float*)d_in[3];
    const float* b_hh0 = (const float*)d_in[4];
    const float* w_ih1 = (const float*)d_in[5];
    const float* w_hh1 = (const float*)d_in[6];
    const float* b_ih1 = (const float*)d_in[7];
    const float* b_hh1 = (const float*)d_in[8];
    const float* fc1_w = (const float*)d_in[9];
    const float* fc1_b = (const float*)d_in[10];
    const float* fc2_w = (const float*)d_in[11];
    const float* fc2_b = (const float*)d_in[12];
    float* out = (float*)d_out;

    const int B = in_sizes[0] / SEQ;   // 4096
    hipLaunchKernelGGL(lstm_kernel, dim3(B / NR), dim3(NTHREADS), 0, stream,
                       x, w_ih0, w_hh0, b_ih0, b_hh0, w_ih1, w_hh1, b_ih1, b_hh1,
                       fc1_w, fc1_b, fc2_w, fc2_b, out);
}

// Round 8
// 311.134 us; speedup vs baseline: 1.1739x; 1.1739x over previous
//
#include <hip/hip_runtime.h>

#define H 32
#define SEQ 512
#define BM 16           // batch rows per block (= MFMA N)
#define NTHREADS 256    // 4 waves; grid = 256 -> 1 block/CU, 1 wave/SIMD
#define HSTRIDE 40      // halves per h-row: 80B rows, 16B-aligned b128 frags

typedef _Float16 half8 __attribute__((ext_vector_type(8)));
typedef __attribute__((ext_vector_type(4))) float f32x4;

#define L2E 1.44269504088896340736f

__device__ __forceinline__ float rcp_(float x)  { return __builtin_amdgcn_rcpf(x); }
__device__ __forceinline__ float exp2_(float x) { return __builtin_amdgcn_exp2f(x); }  // raw v_exp_f32
#define MFMA16(A, B, C) __builtin_amdgcn_mfma_f32_16x16x32_f16((A), (B), (C), 0, 0, 0)

__global__ __launch_bounds__(NTHREADS, 1) void lstm_kernel(
    const float* __restrict__ x,      // [4096,512]
    const float* __restrict__ w_ih0,  // [128,1]
    const float* __restrict__ w_hh0,  // [128,32]
    const float* __restrict__ b_ih0, const float* __restrict__ b_hh0,
    const float* __restrict__ w_ih1,  // [128,32]
    const float* __restrict__ w_hh1,  // [128,32]
    const float* __restrict__ b_ih1, const float* __restrict__ b_hh1,
    const float* __restrict__ fc1_w,  // [16,32]
    const float* __restrict__ fc1_b,  // [16]
    const float* __restrict__ fc2_w,  // [1,16]
    const float* __restrict__ fc2_b,  // [1]
    float* __restrict__ out)          // [4096]
{
    __shared__ __align__(16) float    xbufT[SEQ * BM];         // 32 KB, [step][row]
    __shared__ __align__(16) _Float16 h1s[2][BM * HSTRIDE];    // ping-pong h1 (fp16)
    __shared__ __align__(16) _Float16 h2s[2][BM * HSTRIDE];    // ping-pong h2 (fp16)
    __shared__ __align__(16) float    h2f[BM * 33];
    __shared__ __align__(16) float    yb[BM * 17];

    const int tid  = threadIdx.x;
    const int lane = tid & 63;
    const int wv   = tid >> 6;          // wave id 0..3; owns tiles {wv, wv+4}
    const int c    = lane & 15;         // frag free-index / batch col
    const int q    = lane >> 4;         // k-quad / D row-group
    const int r0   = blockIdx.x * BM;

    // ---- stage x transposed: xbufT[s][row]; 256 threads, 32 steps each ----
    {
        const int row = tid >> 4;           // 0..15
        const int s0  = (tid & 15) * 32;    // 32 steps per thread
        const float* xr = x + (size_t)(r0 + row) * SEQ + s0;
        #pragma unroll
        for (int i = 0; i < 32; i += 4) {
            float4 v = *(const float4*)&xr[i];
            xbufT[(s0 + i + 0) * BM + row] = v.x;
            xbufT[(s0 + i + 1) * BM + row] = v.y;
            xbufT[(s0 + i + 2) * BM + row] = v.z;
            xbufT[(s0 + i + 3) * BM + row] = v.w;
        }
    }
    for (int i = tid; i < BM * HSTRIDE; i += NTHREADS) {
        h1s[0][i] = (_Float16)0.f; h1s[1][i] = (_Float16)0.f;
        h2s[0][i] = (_Float16)0.f; h2s[1][i] = (_Float16)0.f;
    }

    // ---- W fragments (A-operand), rows permuted: tile T frag-row r -> (gate r&3, unit 4T + r>>2)
    // gate scales folded (i,f,o: -L2E ; g: +2L2E) so EW uses raw v_exp_f32.
    const float gsc[4] = { -L2E, -L2E, 2.f * L2E, -L2E };
    const int kb = 8 * q;
    const float wsc = gsc[c & 3];
    const int TA = wv, TB = wv + 4;
    const int wrA = (c & 3) * H + 4 * TA + (c >> 2);
    const int wrB = (c & 3) * H + 4 * TB + (c >> 2);

    half8 w0hA, w0lA, w0hB, w0lB;     // w_hh0
    half8 wihA, wilA, wihB, wilB;     // w_ih1
    half8 whhA, whlA, whhB, whlB;     // w_hh1
    {
        const float *pA, *pB;
        pA = &w_hh0[wrA * H + kb]; pB = &w_hh0[wrB * H + kb];
        #pragma unroll
        for (int j = 0; j < 8; ++j) {
            float vA = pA[j] * wsc; _Float16 hA = (_Float16)vA; w0hA[j] = hA; w0lA[j] = (_Float16)(vA - (float)hA);
            float vB = pB[j] * wsc; _Float16 hB = (_Float16)vB; w0hB[j] = hB; w0lB[j] = (_Float16)(vB - (float)hB);
        }
        pA = &w_ih1[wrA * H + kb]; pB = &w_ih1[wrB * H + kb];
        #pragma unroll
        for (int j = 0; j < 8; ++j) {
            float vA = pA[j] * wsc; _Float16 hA = (_Float16)vA; wihA[j] = hA; wilA[j] = (_Float16)(vA - (float)hA);
            float vB = pB[j] * wsc; _Float16 hB = (_Float16)vB; wihB[j] = hB; wilB[j] = (_Float16)(vB - (float)hB);
        }
        pA = &w_hh1[wrA * H + kb]; pB = &w_hh1[wrB * H + kb];
        #pragma unroll
        for (int j = 0; j < 8; ++j) {
            float vA = pA[j] * wsc; _Float16 hA = (_Float16)vA; whhA[j] = hA; whlA[j] = (_Float16)(vA - (float)hA);
            float vB = pB[j] * wsc; _Float16 hB = (_Float16)vB; whhB[j] = hB; whlB[j] = (_Float16)(vB - (float)hB);
        }
    }

    // per-lane cells: (row c, unit uA) and (row c, unit uB), both layers
    const int uA = 4 * TA + q, uB = 4 * TB + q;
    f32x4 b1A, b1B, b2A, b2B;
    float wxA[4], wxB[4];
    #pragma unroll
    for (int j = 0; j < 4; ++j) {
        b1A[j] = (b_ih0[j * H + uA] + b_hh0[j * H + uA]) * gsc[j];
        b1B[j] = (b_ih0[j * H + uB] + b_hh0[j * H + uB]) * gsc[j];
        b2A[j] = (b_ih1[j * H + uA] + b_hh1[j * H + uA]) * gsc[j];
        b2B[j] = (b_ih1[j * H + uB] + b_hh1[j * H + uB]) * gsc[j];
        wxA[j] = w_ih0[j * H + uA] * gsc[j];
        wxB[j] = w_ih0[j * H + uB] * gsc[j];
    }
    float c1A = 0.f, c1B = 0.f, c2A = 0.f, c2B = 0.f;
    float h2lastA = 0.f, h2lastB = 0.f;

    const int fofs  = c * HSTRIDE + kb;    // b128 frag read offset (halves)
    const int whA   = c * HSTRIDE + uA;    // h write offsets (halves)
    const int whB   = c * HSTRIDE + uB;

    __syncthreads();

    // shared-rcp LSTM cell: 5 v_exp + 2 v_rcp
    auto cell = [&](const f32x4& g, float& cst) -> float {
        float ei = exp2_(g[0]);
        float ef = exp2_(g[1]);
        float eg = exp2_(g[2]);
        float eo = exp2_(g[3]);
        float A  = 1.f + ei;
        float F  = 1.f + ef;
        float Gp = eg + 1.f, Gm = eg - 1.f;
        float t1 = A * Gp;
        float num = fmaf(cst, t1, Gm * F);
        float cn  = num * rcp_(F * t1);
        cn = __builtin_amdgcn_fmed3f(cn, -12.f, 12.f);
        cst = cn;
        float ec = exp2_(cn * (2.f * L2E));
        return (ec - 1.f) * rcp_((1.f + eo) * (ec + 1.f));
    };

    // iter t: L1 step t (tiles A,B), L2 step t-1 (tiles A,B). One 4-wave barrier/iter.
    auto do_step = [&](const _Float16* __restrict__ h1r, const _Float16* __restrict__ h2r,
                       _Float16* __restrict__ h1w, _Float16* __restrict__ h2w,
                       int t, bool e1, bool e2) {
        half8 a1 = *(const half8*)(h1r + fofs);
        half8 a2 = *(const half8*)(h2r + fofs);
        f32x4 g1A = b1A, g1B = b1B, gaA = b2A, gaB = b2B;
        f32x4 gbA = {0.f, 0.f, 0.f, 0.f}, gbB = {0.f, 0.f, 0.f, 0.f};
        // six independent 2-deep MFMA chains
        g1A = MFMA16(w0hA, a1, g1A);  g1B = MFMA16(w0hB, a1, g1B);
        gaA = MFMA16(wihA, a1, gaA);  gaB = MFMA16(wihB, a1, gaB);
        gbA = MFMA16(whhA, a2, gbA);  gbB = MFMA16(whhB, a2, gbB);
        g1A = MFMA16(w0lA, a1, g1A);  g1B = MFMA16(w0lB, a1, g1B);
        gaA = MFMA16(wilA, a1, gaA);  gaB = MFMA16(wilB, a1, gaB);
        gbA = MFMA16(whlA, a2, gbA);  gbB = MFMA16(whlB, a2, gbB);
        if (e1) {
            float xv = xbufT[t * BM + c];
            #pragma unroll
            for (int j = 0; j < 4; ++j) {
                g1A[j] = fmaf(xv, wxA[j], g1A[j]);
                g1B[j] = fmaf(xv, wxB[j], g1B[j]);
            }
            float h1vA = cell(g1A, c1A);
            float h1vB = cell(g1B, c1B);
            h1w[whA] = (_Float16)h1vA;
            h1w[whB] = (_Float16)h1vB;
        }
        if (e2) {
            f32x4 g2A, g2B;
            #pragma unroll
            for (int j = 0; j < 4; ++j) { g2A[j] = gaA[j] + gbA[j]; g2B[j] = gaB[j] + gbB[j]; }
            float h2vA = cell(g2A, c2A);
            float h2vB = cell(g2B, c2B);
            h2lastA = h2vA; h2lastB = h2vB;
            h2w[whA] = (_Float16)h2vA;
            h2w[whB] = (_Float16)h2vB;
        }
        __syncthreads();
    };

    do_step(h1s[0], h2s[0], h1s[1], h2s[1], 0, true, false);
    for (int tt = 0; tt < 255; ++tt) {
        int t = 1 + 2 * tt;
        do_step(h1s[1], h2s[1], h1s[0], h2s[0], t,     true, true);
        do_step(h1s[0], h2s[0], h1s[1], h2s[1], t + 1, true, true);
    }
    do_step(h1s[1], h2s[1], h1s[0], h2s[0], 511, true, true);
    do_step(h1s[0], h2s[0], h1s[1], h2s[1], 512, false, true);

    // ---- FC head: each thread holds 2 h2 cells ----
    h2f[c * 33 + uA] = h2lastA;
    h2f[c * 33 + uB] = h2lastB;
    __syncthreads();
    if (tid < BM * 16) {
        int rr = tid >> 4, j = tid & 15;
        float acc = fc1_b[j];
        #pragma unroll
        for (int k = 0; k < H; ++k) acc += fc1_w[j * H + k] * h2f[rr * 33 + k];
        acc = acc >= 0.f ? acc : 0.2f * acc;
        yb[rr * 17 + j] = acc * fc2_w[j];
    }
    __syncthreads();
    if (tid < BM) {
        float acc = fc2_b[0];
        #pragma unroll
        for (int j = 0; j < 16; ++j) acc += yb[tid * 17 + j];
        out[r0 + tid] = acc;
    }
}

extern "C" void kernel_launch(void* const* d_in, const int* in_sizes, int n_in,
                              void* d_out, int out_size, void* d_ws, size_t ws_size,
                              hipStream_t stream) {
    const float* x     = (const float*)d_in[0];
    const float* w_ih0 = (const float*)d_in[1];
    const float* w_hh0 = (const float*)d_in[2];
    const float* b_ih0 = (const float*)d_in[3];
    const float* b_hh0 = (const float*)d_in[4];
    const float* w_ih1 = (const float*)d_in[5];
    const float* w_hh1 = (const float*)d_in[6];
    const float* b_ih1 = (const float*)d_in[7];
    const float* b_hh1 = (const float*)d_in[8];
    const float* fc1_w = (const float*)d_in[9];
    const float* fc1_b = (const float*)d_in[10];
    const float* fc2_w = (const float*)d_in[11];
    const float* fc2_b = (const float*)d_in[12];
    float* out = (float*)d_out;

    const int B = in_sizes[0] / SEQ;   // 4096
    hipLaunchKernelGGL(lstm_kernel, dim3(B / BM), dim3(NTHREADS), 0, stream,
                       x, w_ih0, w_hh0, b_ih0, b_hh0, w_ih1, w_hh1, b_ih1, b_hh1,
                       fc1_w, fc1_b, fc2_w, fc2_b, out);
}

// Round 9
// 279.552 us; speedup vs baseline: 1.3065x; 1.1130x over previous
//
#include <hip/hip_runtime.h>

#define H 32
#define SEQ 512
#define BM 16          // batch rows per block (= MFMA N)
#define NTHREADS 512   // 8 waves; grid = 256 -> 1 block/CU, 2 waves/SIMD
#define HSTRIDE 40     // halves per h-row: 80B rows, 16B-aligned b128 frags

typedef _Float16 half8 __attribute__((ext_vector_type(8)));
typedef __attribute__((ext_vector_type(4))) float f32x4;

#define L2E 1.44269504088896340736f

__device__ __forceinline__ float rcp_(float x)  { return __builtin_amdgcn_rcpf(x); }
__device__ __forceinline__ float exp2_(float x) { return __builtin_amdgcn_exp2f(x); }  // raw v_exp_f32
#define MFMA16(A, B, C) __builtin_amdgcn_mfma_f32_16x16x32_f16((A), (B), (C), 0, 0, 0)

__global__ __launch_bounds__(NTHREADS, 2) void lstm_kernel(
    const float* __restrict__ x,      // [4096,512]
    const float* __restrict__ w_ih0,  // [128,1]
    const float* __restrict__ w_hh0,  // [128,32]
    const float* __restrict__ b_ih0, const float* __restrict__ b_hh0,
    const float* __restrict__ w_ih1,  // [128,32]
    const float* __restrict__ w_hh1,  // [128,32]
    const float* __restrict__ b_ih1, const float* __restrict__ b_hh1,
    const float* __restrict__ fc1_w,  // [16,32]
    const float* __restrict__ fc1_b,  // [16]
    const float* __restrict__ fc2_w,  // [1,16]
    const float* __restrict__ fc2_b,  // [1]
    float* __restrict__ out)          // [4096]
{
    __shared__ __align__(16) float    xbufT[SEQ * BM];            // 32 KB, [step][row]
    __shared__ __align__(16) _Float16 h1s[2][BM * HSTRIDE];       // ping-pong h1 (fp16), swizzled
    __shared__ __align__(16) _Float16 h2s[2][BM * HSTRIDE];       // ping-pong h2 (fp16), swizzled
    __shared__ __align__(16) float    h2f[BM * 33];
    __shared__ __align__(16) float    yb[BM * 17];

    const int tid  = threadIdx.x;
    const int lane = tid & 63;
    const int wv   = tid >> 6;          // wave id 0..7
    const int c    = lane & 15;         // frag free-index / batch col
    const int q    = lane >> 4;         // k-quad / D row-group
    const int r0   = blockIdx.x * BM;

    // ---- stage x transposed: xbufT[s][row] ----
    {
        const int row = tid >> 5;           // 0..15
        const int s0  = (tid & 31) * 16;    // 16 steps per thread
        const float* xr = x + (size_t)(r0 + row) * SEQ + s0;
        #pragma unroll
        for (int i = 0; i < 16; i += 4) {
            float4 v = *(const float4*)&xr[i];
            xbufT[(s0 + i + 0) * BM + row] = v.x;
            xbufT[(s0 + i + 1) * BM + row] = v.y;
            xbufT[(s0 + i + 2) * BM + row] = v.z;
            xbufT[(s0 + i + 3) * BM + row] = v.w;
        }
    }
    for (int i = tid; i < BM * HSTRIDE; i += NTHREADS) {
        h1s[0][i] = (_Float16)0.f; h1s[1][i] = (_Float16)0.f;
        h2s[0][i] = (_Float16)0.f; h2s[1][i] = (_Float16)0.f;
    }

    // ---- W fragments (A-operand), rows permuted r -> (gate r&3, unit 4wv + r>>2) ----
    // gate scales folded (i,f,o: -L2E ; g: +2L2E) so EW uses raw v_exp_f32.
    const float gsc[4] = { -L2E, -L2E, 2.f * L2E, -L2E };
    const int worig = (c & 3) * H + 4 * wv + (c >> 2);
    const float wsc = gsc[c & 3];
    const int kb = 8 * q;
    half8 w0h, w0l, wih, wil, whh, whl;
    {
        const float* p = &w_hh0[worig * H + kb];
        #pragma unroll
        for (int j = 0; j < 8; ++j) { float v = p[j] * wsc; _Float16 h = (_Float16)v; w0h[j] = h; w0l[j] = (_Float16)(v - (float)h); }
        p = &w_ih1[worig * H + kb];
        #pragma unroll
        for (int j = 0; j < 8; ++j) { float v = p[j] * wsc; _Float16 h = (_Float16)v; wih[j] = h; wil[j] = (_Float16)(v - (float)h); }
        p = &w_hh1[worig * H + kb];
        #pragma unroll
        for (int j = 0; j < 8; ++j) { float v = p[j] * wsc; _Float16 h = (_Float16)v; whh[j] = h; whl[j] = (_Float16)(v - (float)h); }
    }

    // per-lane cell: batch m = c, unit u = 4*wv + q
    const int m = c;
    const int u = 4 * wv + q;
    f32x4 bias1v, bias2v;
    float wx[4];
    #pragma unroll
    for (int g = 0; g < 4; ++g) {
        bias1v[g] = (b_ih0[g * H + u] + b_hh0[g * H + u]) * gsc[g];
        bias2v[g] = (b_ih1[g * H + u] + b_hh1[g * H + u]) * gsc[g];
        wx[g]     = w_ih0[g * H + u] * gsc[g];
    }
    float c1 = 0.f, c2 = 0.f, h2last = 0.f;

    // ---- swizzled LDS addressing: logical h[row][unit] at
    //      row*40 + ((unit>>3)^(row>>3))*8 + (unit&7)   (halves)
    // reads (b128, units 8q..8q+7 of row c) stay contiguous & 16B-aligned;
    // writes lose the m/m+8 bank collision (4-way -> free 2-way).
    const int fofs  = c * HSTRIDE + ((q ^ (c >> 3)) << 3);                    // frag read
    const int whofs = m * HSTRIDE + (((u >> 3) ^ (m >> 3)) << 3) + (u & 7);   // h write

    __syncthreads();

    // single cell (peel steps): 5 exp + 2 rcp
    auto cell1 = [&](const f32x4& g, float& cst) -> float {
        float ei = exp2_(g[0]), ef = exp2_(g[1]), eg = exp2_(g[2]), eo = exp2_(g[3]);
        float A = 1.f + ei, F = 1.f + ef;
        float Gp = eg + 1.f, Gm = eg - 1.f;
        float t1 = A * Gp;
        float num = fmaf(cst, t1, Gm * F);
        float cn  = __builtin_amdgcn_fmed3f(num * rcp_(F * t1), -12.f, 12.f);
        cst = cn;
        float ec = exp2_(cn * (2.f * L2E));
        return (ec - 1.f) * rcp_((1.f + eo) * (ec + 1.f));
    };

    // fused two-cell: 10 exp + 2 shared rcp
    auto cell2 = [&](const f32x4& ga, const f32x4& gb, float& ha, float& hb) {
        float eia = exp2_(ga[0]), efa = exp2_(ga[1]), ega = exp2_(ga[2]), eoa = exp2_(ga[3]);
        float eib = exp2_(gb[0]), efb = exp2_(gb[1]), egb = exp2_(gb[2]), eob = exp2_(gb[3]);
        float Aa = 1.f + eia, Fa = 1.f + efa, Gpa = ega + 1.f, Gma = ega - 1.f;
        float Ab = 1.f + eib, Fb = 1.f + efb, Gpb = egb + 1.f, Gmb = egb - 1.f;
        float t1a = Aa * Gpa,  t1b = Ab * Gpb;
        float Da  = Fa * t1a,  Db  = Fb * t1b;
        float r   = rcp_(Da * Db);
        float na  = fmaf(c1, t1a, Gma * Fa);
        float nb  = fmaf(c2, t1b, Gmb * Fb);
        c1 = __builtin_amdgcn_fmed3f(na * (r * Db), -12.f, 12.f);
        c2 = __builtin_amdgcn_fmed3f(nb * (r * Da), -12.f, 12.f);
        float eca = exp2_(c1 * (2.f * L2E));
        float ecb = exp2_(c2 * (2.f * L2E));
        float Ea  = (1.f + eoa) * (eca + 1.f);
        float Eb  = (1.f + eob) * (ecb + 1.f);
        float r2  = rcp_(Ea * Eb);
        ha = (eca - 1.f) * (r2 * Eb);
        hb = (ecb - 1.f) * (r2 * Ea);
    };

    // iter t: L1 step t, L2 step t-1 (software-pipelined). One barrier/iter.
    auto do_step = [&](const _Float16* __restrict__ h1r, const _Float16* __restrict__ h2r,
                       _Float16* __restrict__ h1w, _Float16* __restrict__ h2w,
                       int t, bool e1, bool e2) {
        half8 a1 = *(const half8*)(h1r + fofs);
        half8 a2 = *(const half8*)(h2r + fofs);
        float xv = 0.f;
        if (e1) xv = xbufT[t * BM + m];
        // g1: 2-deep chain, C = bias (no acc-init copies; D may differ from C)
        f32x4 g1 = MFMA16(w0l, a1, MFMA16(w0h, a1, bias1v));
        // g2: 4-deep chain with C = bias (drops zero-init + 4 adds)
        f32x4 g2 = MFMA16(whl, a2, MFMA16(whh, a2, MFMA16(wil, a1, MFMA16(wih, a1, bias2v))));
        if (e1) {
            #pragma unroll
            for (int j = 0; j < 4; ++j) g1[j] = fmaf(xv, wx[j], g1[j]);
        }
        if (e1 && e2) {
            float h1v, h2v;
            cell2(g1, g2, h1v, h2v);
            h2last = h2v;
            h1w[whofs] = (_Float16)h1v;
            h2w[whofs] = (_Float16)h2v;
        } else if (e1) {
            float h1v = cell1(g1, c1);
            h1w[whofs] = (_Float16)h1v;
        } else if (e2) {
            float h2v = cell1(g2, c2);
            h2last = h2v;
            h2w[whofs] = (_Float16)h2v;
        }
        __syncthreads();
    };

    do_step(h1s[0], h2s[0], h1s[1], h2s[1], 0, true, false);
    for (int tt = 0; tt < 255; ++tt) {
        int t = 1 + 2 * tt;
        do_step(h1s[1], h2s[1], h1s[0], h2s[0], t,     true, true);
        do_step(h1s[0], h2s[0], h1s[1], h2s[1], t + 1, true, true);
    }
    do_step(h1s[1], h2s[1], h1s[0], h2s[0], 511, true, true);
    do_step(h1s[0], h2s[0], h1s[1], h2s[1], 512, false, true);

    // ---- FC head ----
    h2f[m * 33 + u] = h2last;
    __syncthreads();
    if (tid < BM * 16) {
        int rr = tid >> 4, j = tid & 15;
        float acc = fc1_b[j];
        #pragma unroll
        for (int k = 0; k < H; ++k) acc += fc1_w[j * H + k] * h2f[rr * 33 + k];
        acc = acc >= 0.f ? acc : 0.2f * acc;
        yb[rr * 17 + j] = acc * fc2_w[j];
    }
    __syncthreads();
    if (tid < BM) {
        float acc = fc2_b[0];
        #pragma unroll
        for (int j = 0; j < 16; ++j) acc += yb[tid * 17 + j];
        out[r0 + tid] = acc;
    }
}

extern "C" void kernel_launch(void* const* d_in, const int* in_sizes, int n_in,
                              void* d_out, int out_size, void* d_ws, size_t ws_size,
                              hipStream_t stream) {
    const float* x     = (const float*)d_in[0];
    const float* w_ih0 = (const float*)d_in[1];
    const float* w_hh0 = (const float*)d_in[2];
    const float* b_ih0 = (const float*)d_in[3];
    const float* b_hh0 = (const float*)d_in[4];
    const float* w_ih1 = (const float*)d_in[5];
    const float* w_hh1 = (const float*)d_in[6];
    const float* b_ih1 = (const float*)d_in[7];
    const float* b_hh1 = (const float*)d_in[8];
    const float* fc1_w = (const float*)d_in[9];
    const float* fc1_b = (const float*)d_in[10];
    const float* fc2_w = (const float*)d_in[11];
    const float* fc2_b = (const float*)d_in[12];
    float* out = (float*)d_out;

    const int B = in_sizes[0] / SEQ;   // 4096
    hipLaunchKernelGGL(lstm_kernel, dim3(B / BM), dim3(NTHREADS), 0, stream,
                       x, w_ih0, w_hh0, b_ih0, b_hh0, w_ih1, w_hh1, b_ih1, b_hh1,
                       fc1_w, fc1_b, fc2_w, fc2_b, out);
}

// Round 10
// 259.314 us; speedup vs baseline: 1.4085x; 1.0780x over previous
//
#include <hip/hip_runtime.h>

#define H 32
#define SEQ 512
#define BM 16          // batch rows per block (= MFMA N)
#define NTHREADS 512   // 8 waves; grid = 256 -> 1 block/CU, 2 waves/SIMD
#define HSTRIDE 40     // halves per h-row: 80B rows, 16B-aligned b128 frags

typedef _Float16 half8 __attribute__((ext_vector_type(8)));
typedef __attribute__((ext_vector_type(4))) float f32x4;

#define L2E 1.44269504088896340736f

__device__ __forceinline__ float rcp_(float x)  { return __builtin_amdgcn_rcpf(x); }
__device__ __forceinline__ float exp2_(float x) { return __builtin_amdgcn_exp2f(x); }  // raw v_exp_f32
#define MFMA16(A, B, C) __builtin_amdgcn_mfma_f32_16x16x32_f16((A), (B), (C), 0, 0, 0)

__global__ __launch_bounds__(NTHREADS, 2) void lstm_kernel(
    const float* __restrict__ x,      // [4096,512]
    const float* __restrict__ w_ih0,  // [128,1]
    const float* __restrict__ w_hh0,  // [128,32]
    const float* __restrict__ b_ih0, const float* __restrict__ b_hh0,
    const float* __restrict__ w_ih1,  // [128,32]
    const float* __restrict__ w_hh1,  // [128,32]
    const float* __restrict__ b_ih1, const float* __restrict__ b_hh1,
    const float* __restrict__ fc1_w,  // [16,32]
    const float* __restrict__ fc1_b,  // [16]
    const float* __restrict__ fc2_w,  // [1,16]
    const float* __restrict__ fc2_b,  // [1]
    float* __restrict__ out)          // [4096]
{
    __shared__ __align__(16) float    xbufT[SEQ * BM];            // 32 KB, [step][row]
    __shared__ __align__(16) _Float16 h1s[2][BM * HSTRIDE];       // ping-pong h1 (fp16)
    __shared__ __align__(16) _Float16 h2s[2][BM * HSTRIDE];       // ping-pong h2 (fp16)
    __shared__ __align__(16) float    h2f[BM * 33];
    __shared__ __align__(16) float    yb[BM * 17];

    const int tid  = threadIdx.x;
    const int lane = tid & 63;
    const int wv   = tid >> 6;          // wave id 0..7
    const int c    = lane & 15;         // frag free-index / batch col
    const int q    = lane >> 4;         // k-quad / D row-group
    const int r0   = blockIdx.x * BM;

    // ---- stage x transposed: xbufT[s][row] ----
    {
        const int row = tid >> 5;           // 0..15
        const int s0  = (tid & 31) * 16;    // 16 steps per thread
        const float* xr = x + (size_t)(r0 + row) * SEQ + s0;
        #pragma unroll
        for (int i = 0; i < 16; i += 4) {
            float4 v = *(const float4*)&xr[i];
            xbufT[(s0 + i + 0) * BM + row] = v.x;
            xbufT[(s0 + i + 1) * BM + row] = v.y;
            xbufT[(s0 + i + 2) * BM + row] = v.z;
            xbufT[(s0 + i + 3) * BM + row] = v.w;
        }
    }
    for (int i = tid; i < BM * HSTRIDE; i += NTHREADS) {
        h1s[0][i] = (_Float16)0.f; h1s[1][i] = (_Float16)0.f;
        h2s[0][i] = (_Float16)0.f; h2s[1][i] = (_Float16)0.f;
    }

    // ---- W fragments (A-operand), single fp16, rows permuted r -> (gate r&3, unit 4wv + r>>2)
    // gate scales folded (i,f,o: -L2E ; g: +2L2E) so EW uses raw v_exp_f32.
    const float gsc[4] = { -L2E, -L2E, 2.f * L2E, -L2E };
    const int worig = (c & 3) * H + 4 * wv + (c >> 2);
    const float wsc = gsc[c & 3];
    const int kb = 8 * q;
    half8 w0, wih, whh;
    {
        const float* p = &w_hh0[worig * H + kb];
        #pragma unroll
        for (int j = 0; j < 8; ++j) w0[j]  = (_Float16)(p[j] * wsc);
        p = &w_ih1[worig * H + kb];
        #pragma unroll
        for (int j = 0; j < 8; ++j) wih[j] = (_Float16)(p[j] * wsc);
        p = &w_hh1[worig * H + kb];
        #pragma unroll
        for (int j = 0; j < 8; ++j) whh[j] = (_Float16)(p[j] * wsc);
    }

    // per-lane cell: batch m = c, unit u = 4*wv + q
    const int m = c;
    const int u = 4 * wv + q;
    f32x4 bias1v, bias2v;
    float wx[4];
    #pragma unroll
    for (int g = 0; g < 4; ++g) {
        bias1v[g] = (b_ih0[g * H + u] + b_hh0[g * H + u]) * gsc[g];
        bias2v[g] = (b_ih1[g * H + u] + b_hh1[g * H + u]) * gsc[g];
        wx[g]     = w_ih0[g * H + u] * gsc[g];
    }
    float c1 = 0.f, c2 = 0.f, h2last = 0.f;

    const int fofs  = c * HSTRIDE + kb;   // b128 frag read offset (halves)
    const int whofs = m * HSTRIDE + u;    // h write offset (halves)

    __syncthreads();

    // LSTM cell: 5 v_exp + 2 v_rcp; exp-arg clamp keeps c-state path short and
    // guards fp32 overflow (arg<=80 -> h -> +-1/(1+eo), the correct limit).
    auto cell = [&](const f32x4& g, float& cst) -> float {
        float ei = exp2_(g[0]), ef = exp2_(g[1]), eg = exp2_(g[2]), eo = exp2_(g[3]);
        float A  = 1.f + ei, F = 1.f + ef;
        float Gp = eg + 1.f, Gm = eg - 1.f;
        float t1 = A * Gp;
        float num = fmaf(cst, t1, Gm * F);
        float cn  = num * rcp_(F * t1);
        cst = cn;
        float ec = exp2_(fminf(cn * (2.f * L2E), 80.f));
        return (ec - 1.f) * rcp_((1.f + eo) * (ec + 1.f));
    };

    // iter t: L1 step t, L2 step t-1 (software-pipelined). One barrier/iter.
    auto do_step = [&](const _Float16* __restrict__ h1r, const _Float16* __restrict__ h2r,
                       _Float16* __restrict__ h1w, _Float16* __restrict__ h2w,
                       int t, bool e1, bool e2) {
        half8 a1 = *(const half8*)(h1r + fofs);
        half8 a2 = *(const half8*)(h2r + fofs);
        float xv = 0.f;
        if (e1) xv = xbufT[t * BM + m];
        // g1: 1-deep, C = bias; g2: 2-deep, C = bias
        f32x4 g1 = MFMA16(w0, a1, bias1v);
        f32x4 g2 = MFMA16(whh, a2, MFMA16(wih, a1, bias2v));
        if (e1) {
            #pragma unroll
            for (int j = 0; j < 4; ++j) g1[j] = fmaf(xv, wx[j], g1[j]);
            float h1v = cell(g1, c1);
            h1w[whofs] = (_Float16)h1v;     // write h1 the moment its chain ends
        }
        if (e2) {
            float h2v = cell(g2, c2);
            h2last = h2v;
            h2w[whofs] = (_Float16)h2v;
        }
        __syncthreads();
    };

    do_step(h1s[0], h2s[0], h1s[1], h2s[1], 0, true, false);
    for (int tt = 0; tt < 255; ++tt) {
        int t = 1 + 2 * tt;
        do_step(h1s[1], h2s[1], h1s[0], h2s[0], t,     true, true);
        do_step(h1s[0], h2s[0], h1s[1], h2s[1], t + 1, true, true);
    }
    do_step(h1s[1], h2s[1], h1s[0], h2s[0], 511, true, true);
    do_step(h1s[0], h2s[0], h1s[1], h2s[1], 512, false, true);

    // ---- FC head ----
    h2f[m * 33 + u] = h2last;
    __syncthreads();
    if (tid < BM * 16) {
        int rr = tid >> 4, j = tid & 15;
        float acc = fc1_b[j];
        #pragma unroll
        for (int k = 0; k < H; ++k) acc += fc1_w[j * H + k] * h2f[rr * 33 + k];
        acc = acc >= 0.f ? acc : 0.2f * acc;
        yb[rr * 17 + j] = acc * fc2_w[j];
    }
    __syncthreads();
    if (tid < BM) {
        float acc = fc2_b[0];
        #pragma unroll
        for (int j = 0; j < 16; ++j) acc += yb[tid * 17 + j];
        out[r0 + tid] = acc;
    }
}

extern "C" void kernel_launch(void* const* d_in, const int* in_sizes, int n_in,
                              void* d_out, int out_size, void* d_ws, size_t ws_size,
                              hipStream_t stream) {
    const float* x     = (const float*)d_in[0];
    const float* w_ih0 = (const float*)d_in[1];
    const float* w_hh0 = (const float*)d_in[2];
    const float* b_ih0 = (const float*)d_in[3];
    const float* b_hh0 = (const float*)d_in[4];
    const float* w_ih1 = (const float*)d_in[5];
    const float* w_hh1 = (const float*)d_in[6];
    const float* b_ih1 = (const float*)d_in[7];
    const float* b_hh1 = (const float*)d_in[8];
    const float* fc1_w = (const float*)d_in[9];
    const float* fc1_b = (const float*)d_in[10];
    const float* fc2_w = (const float*)d_in[11];
    const float* fc2_b = (const float*)d_in[12];
    float* out = (float*)d_out;

    const int B = in_sizes[0] / SEQ;   // 4096
    hipLaunchKernelGGL(lstm_kernel, dim3(B / BM), dim3(NTHREADS), 0, stream,
                       x, w_ih0, w_hh0, b_ih0, b_hh0, w_ih1, w_hh1, b_ih1, b_hh1,
                       fc1_w, fc1_b, fc2_w, fc2_b, out);
}